// Round 6
// baseline (967.437 us; speedup 1.0000x reference)
//
#include <hip/hip_runtime.h>
#include <hip/hip_bf16.h>
#include <stdint.h>

#define D_VIT 768
#define D_SAE 12288
#define TOPK 32
#define NC 48          // candidate superset target
#define CMAX 128

typedef __attribute__((ext_vector_type(8))) short bf8_t;   // 8 bf16 (4 VGPRs)
typedef __attribute__((ext_vector_type(4))) float f4_t;    // 4 f32 acc
typedef __attribute__((ext_vector_type(2))) unsigned int u32x2;
typedef __attribute__((ext_vector_type(4))) unsigned int u32x4;
typedef const __attribute__((address_space(1))) void* gas_t;
typedef __attribute__((address_space(3))) void* las_t;

// ---------------- transpose W_enc (768 x 12288) -> wt f32 + wtb bf16 ---------
__global__ void k_transpose(const float* __restrict__ src, float* __restrict__ dst,
                            __hip_bfloat16* __restrict__ dstb) {
    __shared__ float t[32][33];
    int f0 = blockIdx.x * 32, k0 = blockIdx.y * 32;
    int tx = threadIdx.x, ty = threadIdx.y;
#pragma unroll
    for (int j = 0; j < 32; j += 8)
        t[ty + j][tx] = src[(size_t)(k0 + ty + j) * D_SAE + f0 + tx];
    __syncthreads();
#pragma unroll
    for (int j = 0; j < 32; j += 8) {
        float v = t[tx][ty + j];
        dst[(size_t)(f0 + ty + j) * D_VIT + k0 + tx] = v;
        dstb[(size_t)(f0 + ty + j) * D_VIT + k0 + tx] = __float2bfloat16(v);
    }
}

// ---------------- xb = bf16(x - b_dec) ---------------------------------------
__global__ __launch_bounds__(256) void k_cvt_x(const float* __restrict__ x,
    const float* __restrict__ bdec, __hip_bfloat16* __restrict__ xb, long long n) {
    long long i = ((long long)blockIdx.x * 256 + threadIdx.x) * 8;
    if (i >= n) return;
    float4 a = *reinterpret_cast<const float4*>(x + i);
    float4 b = *reinterpret_cast<const float4*>(x + i + 4);
    int kk = (int)(i % D_VIT);
    float4 c = *reinterpret_cast<const float4*>(bdec + kk);
    float4 d = *reinterpret_cast<const float4*>(bdec + kk + 4);
    union { __hip_bfloat16 h[8]; uint4 v; } o;
    o.h[0] = __float2bfloat16(a.x - c.x); o.h[1] = __float2bfloat16(a.y - c.y);
    o.h[2] = __float2bfloat16(a.z - c.z); o.h[3] = __float2bfloat16(a.w - c.w);
    o.h[4] = __float2bfloat16(b.x - d.x); o.h[5] = __float2bfloat16(b.y - d.y);
    o.h[6] = __float2bfloat16(b.z - d.z); o.h[7] = __float2bfloat16(b.w - d.w);
    *reinterpret_cast<uint4*>(xb + i) = o.v;
}

// ---------------- MFMA encoder: actsb = bf16(relu(xb @ wtb^T)) ---------------
#define EBM 128
#define EBN 128
#define EBK 64

__global__ __launch_bounds__(256) void k_enc_mfma(
    const __hip_bfloat16* __restrict__ xb, const __hip_bfloat16* __restrict__ wtb,
    __hip_bfloat16* __restrict__ actsb, int row0, int mrows, int Mtot,
    int gx, int gy) {
    __shared__ __hip_bfloat16 As[EBM * EBK];
    __shared__ __hip_bfloat16 Bs[EBN * EBK];
    int tid = threadIdx.x;
    int lane = tid & 63, w = tid >> 6;
    int wm = w >> 1, wn = w & 1;

    // bijective XCD-chunked swizzle (m204): consecutive blocks on one XCD
    // share the A row-tile -> L2 locality.
    int nwg = gx * gy;
    int lid = blockIdx.x;
    int q = nwg >> 3, r = nwg & 7;
    int xcd = lid & 7, off = lid >> 3;
    int sw = (xcd < r ? xcd * (q + 1) : r * (q + 1) + (xcd - r) * q) + off;
    int bn = sw % gx, bm = sw / gx;
    int tile_m = bm * EBM, tile_n = bn * EBN;

    f4_t acc[4][4] = {};

#pragma unroll 1
    for (int k0 = 0; k0 < D_VIT; k0 += EBK) {
#pragma unroll
        for (int j = 0; j < 4; ++j) {
            int G = w * 64 + j * 256 + lane;
            int rr = G >> 3, g = G & 7;
            int gg = g ^ (rr & 7);
            int ar = row0 + tile_m + rr; if (ar >= Mtot) ar = Mtot - 1;
            const __hip_bfloat16* ga = xb + (size_t)ar * D_VIT + k0 + gg * 8;
            __builtin_amdgcn_global_load_lds((gas_t)ga,
                (las_t)(As + (w * 64 + j * 256) * 8), 16, 0, 0);
            const __hip_bfloat16* gb = wtb + (size_t)(tile_n + rr) * D_VIT + k0 + gg * 8;
            __builtin_amdgcn_global_load_lds((gas_t)gb,
                (las_t)(Bs + (w * 64 + j * 256) * 8), 16, 0, 0);
        }
        __syncthreads();

        int lrow = lane & 15, lk = lane >> 4;
#pragma unroll
        for (int half = 0; half < 2; ++half) {
            int g = lk + half * 4;
            bf8_t af[4], bfr[4];
#pragma unroll
            for (int f = 0; f < 4; ++f) {
                int rr = wm * 64 + f * 16 + lrow;
                af[f] = *reinterpret_cast<const bf8_t*>(As + rr * EBK + ((g ^ (lrow & 7)) << 3));
                int rn = wn * 64 + f * 16 + lrow;
                bfr[f] = *reinterpret_cast<const bf8_t*>(Bs + rn * EBK + ((g ^ (lrow & 7)) << 3));
            }
#pragma unroll
            for (int i = 0; i < 4; ++i)
#pragma unroll
                for (int jn = 0; jn < 4; ++jn)
                    acc[i][jn] = __builtin_amdgcn_mfma_f32_16x16x32_bf16(
                        bfr[jn], af[i], acc[i][jn], 0, 0, 0);
        }
        __syncthreads();
    }

    // D[feature][xrow]: feature = (lane>>4)*4 + q, xrow = lane&15; nt stores
#pragma unroll
    for (int i = 0; i < 4; ++i) {
        int xr = tile_m + wm * 64 + i * 16 + (lane & 15);
        if (xr < mrows) {
            __hip_bfloat16* rowp = actsb + (size_t)xr * D_SAE;
#pragma unroll
            for (int jn = 0; jn < 4; ++jn) {
                int fb = tile_n + wn * 64 + jn * 16 + ((lane >> 4) << 2);
                union { __hip_bfloat16 h[4]; u32x2 u; } o;
                o.h[0] = __float2bfloat16(fmaxf(acc[i][jn][0], 0.f));
                o.h[1] = __float2bfloat16(fmaxf(acc[i][jn][1], 0.f));
                o.h[2] = __float2bfloat16(fmaxf(acc[i][jn][2], 0.f));
                o.h[3] = __float2bfloat16(fmaxf(acc[i][jn][3], 0.f));
                __builtin_nontemporal_store(o.u, reinterpret_cast<u32x2*>(rowp + fb));
            }
        }
    }
}

// -------- per-row: two-level exact-code threshold, f64 rerank, rank, decode --
__global__ __launch_bounds__(256) void k_select(
    const __hip_bfloat16* __restrict__ actsb, const float* __restrict__ x,
    const float* __restrict__ bdec, const float* __restrict__ wt,
    const float* __restrict__ wdec, float* __restrict__ out,
    int row0, int mrows) {
    int lrow = blockIdx.x;
    int row = row0 + lrow;
    int tid = threadIdx.x;

    __shared__ float xs[D_VIT];
    __shared__ unsigned int hist1[256];
    __shared__ unsigned int hist2[128];
    __shared__ int cand[CMAX];
    __shared__ double cval[CMAX];
    __shared__ float sval[TOPK];
    __shared__ int sidx[TOPK];
    __shared__ int s_cnt, s_b1, s_code;
    __shared__ unsigned int s_above;

    hist1[tid] = 0;
    if (tid < 128) hist2[tid] = 0;
    if (tid < TOPK) { sval[tid] = 0.f; sidx[tid] = 0; }
    if (tid == 0) { s_cnt = 0; s_b1 = -1; s_code = 1; s_above = 0; }
    for (int i = tid; i < D_VIT; i += 256)
        xs[i] = __builtin_nontemporal_load(x + (size_t)row * D_VIT + i) - bdec[i];

    u32x4 u[6];
    const u32x4* arow = reinterpret_cast<const u32x4*>(actsb + (size_t)lrow * D_SAE);
#pragma unroll
    for (int j = 0; j < 6; ++j) u[j] = __builtin_nontemporal_load(arow + 256 * j + tid);
    __syncthreads();

    // level-1 histogram: 256 bins over code>>7 (positives only)
#pragma unroll
    for (int j = 0; j < 6; ++j) {
#pragma unroll
        for (int p = 0; p < 4; ++p) {
            unsigned int wp = u[j][p];
            unsigned int h0 = wp & 0xffffu, h1 = wp >> 16;
            if (h0 && h0 < 0x8000u) atomicAdd(&hist1[h0 >> 7], 1u);
            if (h1 && h1 < 0x8000u) atomicAdd(&hist1[h1 >> 7], 1u);
        }
    }
    __syncthreads();

    // wave-0 suffix scan over 256 bins (4 per lane)
    if (tid < 64) {
        int l = tid;
        unsigned c0 = hist1[4 * l], c1 = hist1[4 * l + 1],
                 c2 = hist1[4 * l + 2], c3 = hist1[4 * l + 3];
        unsigned S = c0 + c1 + c2 + c3;
#pragma unroll
        for (int o = 1; o < 64; o <<= 1) {
            unsigned t = __shfl_down(S, o);
            if (l + o < 64) S += t;
        }
        unsigned above = __shfl_down(S, 1);
        if (l == 63) above = 0;
        if (S >= NC && above < NC) {
            int b1; unsigned ab;
            if (above + c3 >= NC)                 { b1 = 4 * l + 3; ab = above; }
            else if (above + c3 + c2 >= NC)       { b1 = 4 * l + 2; ab = above + c3; }
            else if (above + c3 + c2 + c1 >= NC)  { b1 = 4 * l + 1; ab = above + c3 + c2; }
            else                                  { b1 = 4 * l;     ab = above + c3 + c2 + c1; }
            s_b1 = b1; s_above = ab;
        }
    }
    __syncthreads();
    int b1 = s_b1;

    if (b1 >= 0) {
        // level-2 histogram: 128 sub-codes within bin b1
#pragma unroll
        for (int j = 0; j < 6; ++j) {
#pragma unroll
            for (int p = 0; p < 4; ++p) {
                unsigned int wp = u[j][p];
                unsigned int h0 = wp & 0xffffu, h1 = wp >> 16;
                if (h0 && h0 < 0x8000u && (int)(h0 >> 7) == b1) atomicAdd(&hist2[h0 & 127u], 1u);
                if (h1 && h1 < 0x8000u && (int)(h1 >> 7) == b1) atomicAdd(&hist2[h1 & 127u], 1u);
            }
        }
        __syncthreads();
        if (tid < 64) {
            int l = tid;
            unsigned above0 = s_above;
            unsigned c0 = hist2[2 * l], c1 = hist2[2 * l + 1];
            unsigned S = c0 + c1;
#pragma unroll
            for (int o = 1; o < 64; o <<= 1) {
                unsigned t = __shfl_down(S, o);
                if (l + o < 64) S += t;
            }
            unsigned ab2 = __shfl_down(S, 1);
            if (l == 63) ab2 = 0;
            if (above0 + S >= NC && above0 + ab2 < NC) {
                if (above0 + ab2 + c1 >= NC) s_code = (b1 << 7) | (2 * l + 1);
                else                         s_code = (b1 << 7) | (2 * l);
            }
        }
        __syncthreads();
    }
    int code = s_code;

    // compact candidates: all positives with code >= threshold
#pragma unroll
    for (int j = 0; j < 6; ++j) {
#pragma unroll
        for (int p = 0; p < 4; ++p) {
            unsigned int wp = u[j][p];
            unsigned int h0 = wp & 0xffffu, h1 = wp >> 16;
            if (h0 < 0x8000u && (int)h0 >= code) {
                int slot = atomicAdd(&s_cnt, 1);
                if (slot < CMAX) cand[slot] = j * 2048 + tid * 8 + p * 2;
            }
            if (h1 < 0x8000u && (int)h1 >= code) {
                int slot = atomicAdd(&s_cnt, 1);
                if (slot < CMAX) cand[slot] = j * 2048 + tid * 8 + p * 2 + 1;
            }
        }
    }
    __syncthreads();
    int C = s_cnt < CMAX ? s_cnt : CMAX;

    // exact f64 rerank: 4 threads per candidate (wt stays cache-resident)
    for (int base = 0; base < C; base += 64) {
        int c = base + (tid >> 2), sub = tid & 3;
        if (c < C) {
            const float* wr = wt + (size_t)cand[c] * D_VIT;
            double acc = 0.0;
            for (int k = sub * 4; k < D_VIT; k += 16) {
                float4 wv = *reinterpret_cast<const float4*>(wr + k);
                float4 xv = *reinterpret_cast<const float4*>(xs + k);
                acc += (double)wv.x * xv.x + (double)wv.y * xv.y
                     + (double)wv.z * xv.z + (double)wv.w * xv.w;
            }
            acc += __shfl_xor(acc, 1);
            acc += __shfl_xor(acc, 2);
            if (sub == 0) cval[c] = acc > 0.0 ? acc : 0.0;
        }
    }
    __syncthreads();

    // parallel rank-routing (deterministic regardless of cand order)
    if (tid < C) {
        double mv = cval[tid]; int mi = cand[tid];
        int rank = 0;
        for (int j = 0; j < C; ++j) {
            double vj = cval[j];
            rank += (vj > mv) || (vj == mv && cand[j] < mi);
        }
        if (rank < TOPK) { sval[rank] = (float)mv; sidx[rank] = mi; }
    }
    __syncthreads();

    // sparse decode + b_dec; nt store for out
    for (int d = tid; d < D_VIT; d += 256) {
        float o = bdec[d];
#pragma unroll
        for (int j = 0; j < TOPK; j++)
            o = fmaf(sval[j], wdec[(size_t)sidx[j] * D_VIT + d], o);
        __builtin_nontemporal_store(o, out + (size_t)row * D_VIT + d);
    }
}

extern "C" void kernel_launch(void* const* d_in, const int* in_sizes, int n_in,
                              void* d_out, int out_size, void* d_ws, size_t ws_size,
                              hipStream_t stream) {
    const float* x    = (const float*)d_in[0];
    const float* wenc = (const float*)d_in[1];
    const float* wdec = (const float*)d_in[2];
    const float* bdec = (const float*)d_in[3];
    float* out = (float*)d_out;
    int M = in_sizes[0] / D_VIT;

    size_t wt_b  = (size_t)D_SAE * D_VIT * sizeof(float);
    size_t wtb_b = (size_t)D_SAE * D_VIT * sizeof(__hip_bfloat16);
    size_t xb_b  = (size_t)M * D_VIT * sizeof(__hip_bfloat16);
    size_t fixed = wt_b + wtb_b + xb_b;
    size_t row_b = (size_t)D_SAE * sizeof(__hip_bfloat16);

    float* wt            = (float*)d_ws;
    __hip_bfloat16* wtb  = (__hip_bfloat16*)((char*)d_ws + wt_b);
    __hip_bfloat16* xb   = (__hip_bfloat16*)((char*)d_ws + wt_b + wtb_b);
    __hip_bfloat16* actb = (__hip_bfloat16*)((char*)d_ws + fixed);

    long long chl = (long long)((ws_size > fixed ? ws_size - fixed : row_b) / row_b);
    int CH = (int)(chl < 1 ? 1 : (chl > (long long)M ? M : chl));
    if (CH >= 128 && CH < M) CH &= ~127;

    {
        dim3 g(D_SAE / 32, D_VIT / 32), b(32, 8);
        hipLaunchKernelGGL(k_transpose, g, b, 0, stream, wenc, wt, wtb);
    }
    {
        long long n = (long long)M * D_VIT;
        int blocks = (int)((n / 8 + 255) / 256);
        hipLaunchKernelGGL(k_cvt_x, dim3(blocks), dim3(256), 0, stream, x, bdec, xb, n);
    }
    for (int s = 0; s < M; s += CH) {
        int mr = (M - s) < CH ? (M - s) : CH;
        int gx = D_SAE / EBN, gy = (mr + EBM - 1) / EBM;
        hipLaunchKernelGGL(k_enc_mfma, dim3(gx * gy), dim3(256), 0, stream,
                           xb, wtb, actb, s, mr, M, gx, gy);
        hipLaunchKernelGGL(k_select, dim3(mr), dim3(256), 0, stream,
                           actb, x, bdec, wt, wdec, out, s, mr);
    }
}

// Round 7
// 884.668 us; speedup vs baseline: 1.0936x; 1.0936x over previous
//
#include <hip/hip_runtime.h>
#include <hip/hip_bf16.h>
#include <stdint.h>

#define D_VIT 768
#define D_SAE 12288
#define TOPK 32
#define NC 48          // candidate superset target
#define CMAX 128
#define CHMAX 4096     // rows per chunk: acts chunk 100MB + wt+wdec 75MB < L3

typedef __attribute__((ext_vector_type(8))) short bf8_t;   // 8 bf16 (4 VGPRs)
typedef __attribute__((ext_vector_type(4))) float f4_t;    // 4 f32 acc
typedef __attribute__((ext_vector_type(4))) unsigned int u32x4;
typedef const __attribute__((address_space(1))) void* gas_t;
typedef __attribute__((address_space(3))) void* las_t;

// ---------------- transpose W_enc (768 x 12288) -> wt f32 + wtb bf16 ---------
__global__ void k_transpose(const float* __restrict__ src, float* __restrict__ dst,
                            __hip_bfloat16* __restrict__ dstb) {
    __shared__ float t[32][33];
    int f0 = blockIdx.x * 32, k0 = blockIdx.y * 32;
    int tx = threadIdx.x, ty = threadIdx.y;
#pragma unroll
    for (int j = 0; j < 32; j += 8)
        t[ty + j][tx] = src[(size_t)(k0 + ty + j) * D_SAE + f0 + tx];
    __syncthreads();
#pragma unroll
    for (int j = 0; j < 32; j += 8) {
        float v = t[tx][ty + j];
        dst[(size_t)(f0 + ty + j) * D_VIT + k0 + tx] = v;
        dstb[(size_t)(f0 + ty + j) * D_VIT + k0 + tx] = __float2bfloat16(v);
    }
}

// ---------------- xb = bf16(x - b_dec) ---------------------------------------
__global__ __launch_bounds__(256) void k_cvt_x(const float* __restrict__ x,
    const float* __restrict__ bdec, __hip_bfloat16* __restrict__ xb, long long n) {
    long long i = ((long long)blockIdx.x * 256 + threadIdx.x) * 8;
    if (i >= n) return;
    float4 a = *reinterpret_cast<const float4*>(x + i);
    float4 b = *reinterpret_cast<const float4*>(x + i + 4);
    int kk = (int)(i % D_VIT);
    float4 c = *reinterpret_cast<const float4*>(bdec + kk);
    float4 d = *reinterpret_cast<const float4*>(bdec + kk + 4);
    union { __hip_bfloat16 h[8]; uint4 v; } o;
    o.h[0] = __float2bfloat16(a.x - c.x); o.h[1] = __float2bfloat16(a.y - c.y);
    o.h[2] = __float2bfloat16(a.z - c.z); o.h[3] = __float2bfloat16(a.w - c.w);
    o.h[4] = __float2bfloat16(b.x - d.x); o.h[5] = __float2bfloat16(b.y - d.y);
    o.h[6] = __float2bfloat16(b.z - d.z); o.h[7] = __float2bfloat16(b.w - d.w);
    *reinterpret_cast<uint4*>(xb + i) = o.v;
}

// ---------------- MFMA encoder: actsb = bf16(relu(xb @ wtb^T)) ---------------
#define EBM 128
#define EBN 128
#define EBK 64

__global__ __launch_bounds__(256) void k_enc_mfma(
    const __hip_bfloat16* __restrict__ xb, const __hip_bfloat16* __restrict__ wtb,
    __hip_bfloat16* __restrict__ actsb, int row0, int mrows, int Mtot) {
    __shared__ __hip_bfloat16 As[EBM * EBK];
    __shared__ __hip_bfloat16 Bs[EBN * EBK];
    int tid = threadIdx.x;
    int lane = tid & 63, w = tid >> 6;
    int wm = w >> 1, wn = w & 1;
    int tile_m = blockIdx.y * EBM, tile_n = blockIdx.x * EBN;

    f4_t acc[4][4] = {};

#pragma unroll 1
    for (int k0 = 0; k0 < D_VIT; k0 += EBK) {
#pragma unroll
        for (int j = 0; j < 4; ++j) {
            int G = w * 64 + j * 256 + lane;
            int rr = G >> 3, g = G & 7;
            int gg = g ^ (rr & 7);
            int ar = row0 + tile_m + rr; if (ar >= Mtot) ar = Mtot - 1;
            const __hip_bfloat16* ga = xb + (size_t)ar * D_VIT + k0 + gg * 8;
            __builtin_amdgcn_global_load_lds((gas_t)ga,
                (las_t)(As + (w * 64 + j * 256) * 8), 16, 0, 0);
            const __hip_bfloat16* gb = wtb + (size_t)(tile_n + rr) * D_VIT + k0 + gg * 8;
            __builtin_amdgcn_global_load_lds((gas_t)gb,
                (las_t)(Bs + (w * 64 + j * 256) * 8), 16, 0, 0);
        }
        __syncthreads();

        int lrow = lane & 15, lk = lane >> 4;
#pragma unroll
        for (int half = 0; half < 2; ++half) {
            int g = lk + half * 4;
            bf8_t af[4], bfr[4];
#pragma unroll
            for (int f = 0; f < 4; ++f) {
                int rr = wm * 64 + f * 16 + lrow;
                af[f] = *reinterpret_cast<const bf8_t*>(As + rr * EBK + ((g ^ (lrow & 7)) << 3));
                int rn = wn * 64 + f * 16 + lrow;
                bfr[f] = *reinterpret_cast<const bf8_t*>(Bs + rn * EBK + ((g ^ (lrow & 7)) << 3));
            }
#pragma unroll
            for (int i = 0; i < 4; ++i)
#pragma unroll
                for (int jn = 0; jn < 4; ++jn)
                    acc[i][jn] = __builtin_amdgcn_mfma_f32_16x16x32_bf16(
                        bfr[jn], af[i], acc[i][jn], 0, 0, 0);
        }
        __syncthreads();
    }

    // D[feature][xrow]: feature = (lane>>4)*4 + q, xrow = lane&15; cached stores
#pragma unroll
    for (int i = 0; i < 4; ++i) {
        int xr = tile_m + wm * 64 + i * 16 + (lane & 15);
        if (xr < mrows) {
            __hip_bfloat16* rowp = actsb + (size_t)xr * D_SAE;
#pragma unroll
            for (int jn = 0; jn < 4; ++jn) {
                int fb = tile_n + wn * 64 + jn * 16 + ((lane >> 4) << 2);
                union { __hip_bfloat16 h[4]; uint2 u; } o;
                o.h[0] = __float2bfloat16(fmaxf(acc[i][jn][0], 0.f));
                o.h[1] = __float2bfloat16(fmaxf(acc[i][jn][1], 0.f));
                o.h[2] = __float2bfloat16(fmaxf(acc[i][jn][2], 0.f));
                o.h[3] = __float2bfloat16(fmaxf(acc[i][jn][3], 0.f));
                *reinterpret_cast<uint2*>(rowp + fb) = o.u;
            }
        }
    }
}

// -------- per-row: two-level exact-code threshold, f64 rerank, rank, decode --
__global__ __launch_bounds__(256) void k_select(
    const __hip_bfloat16* __restrict__ actsb, const float* __restrict__ x,
    const float* __restrict__ bdec, const float* __restrict__ wt,
    const float* __restrict__ wdec, float* __restrict__ out,
    int row0, int mrows) {
    int lrow = blockIdx.x;
    int row = row0 + lrow;
    int tid = threadIdx.x;

    __shared__ float xs[D_VIT];
    __shared__ unsigned int hist1[256];
    __shared__ unsigned int hist2[128];
    __shared__ int cand[CMAX];
    __shared__ double cval[CMAX];
    __shared__ float sval[TOPK];
    __shared__ int sidx[TOPK];
    __shared__ int s_cnt, s_b1, s_code;
    __shared__ unsigned int s_above;

    hist1[tid] = 0;
    if (tid < 128) hist2[tid] = 0;
    if (tid < TOPK) { sval[tid] = 0.f; sidx[tid] = 0; }
    if (tid == 0) { s_cnt = 0; s_b1 = -1; s_code = 1; s_above = 0; }
    for (int i = tid; i < D_VIT; i += 256)
        xs[i] = x[(size_t)row * D_VIT + i] - bdec[i];

    u32x4 u[6];
    const u32x4* arow = reinterpret_cast<const u32x4*>(actsb + (size_t)lrow * D_SAE);
#pragma unroll
    for (int j = 0; j < 6; ++j) u[j] = arow[256 * j + tid];
    __syncthreads();

    // level-1 histogram: 256 bins over code>>7 (positives only)
#pragma unroll
    for (int j = 0; j < 6; ++j) {
#pragma unroll
        for (int p = 0; p < 4; ++p) {
            unsigned int wp = u[j][p];
            unsigned int h0 = wp & 0xffffu, h1 = wp >> 16;
            if (h0 && h0 < 0x8000u) atomicAdd(&hist1[h0 >> 7], 1u);
            if (h1 && h1 < 0x8000u) atomicAdd(&hist1[h1 >> 7], 1u);
        }
    }
    __syncthreads();

    // wave-0 suffix scan over 256 bins (4 per lane)
    if (tid < 64) {
        int l = tid;
        unsigned c0 = hist1[4 * l], c1 = hist1[4 * l + 1],
                 c2 = hist1[4 * l + 2], c3 = hist1[4 * l + 3];
        unsigned S = c0 + c1 + c2 + c3;
#pragma unroll
        for (int o = 1; o < 64; o <<= 1) {
            unsigned t = __shfl_down(S, o);
            if (l + o < 64) S += t;
        }
        unsigned above = __shfl_down(S, 1);
        if (l == 63) above = 0;
        if (S >= NC && above < NC) {
            int b1; unsigned ab;
            if (above + c3 >= NC)                 { b1 = 4 * l + 3; ab = above; }
            else if (above + c3 + c2 >= NC)       { b1 = 4 * l + 2; ab = above + c3; }
            else if (above + c3 + c2 + c1 >= NC)  { b1 = 4 * l + 1; ab = above + c3 + c2; }
            else                                  { b1 = 4 * l;     ab = above + c3 + c2 + c1; }
            s_b1 = b1; s_above = ab;
        }
    }
    __syncthreads();
    int b1 = s_b1;

    if (b1 >= 0) {
        // level-2 histogram: 128 sub-codes within bin b1
#pragma unroll
        for (int j = 0; j < 6; ++j) {
#pragma unroll
            for (int p = 0; p < 4; ++p) {
                unsigned int wp = u[j][p];
                unsigned int h0 = wp & 0xffffu, h1 = wp >> 16;
                if (h0 && h0 < 0x8000u && (int)(h0 >> 7) == b1) atomicAdd(&hist2[h0 & 127u], 1u);
                if (h1 && h1 < 0x8000u && (int)(h1 >> 7) == b1) atomicAdd(&hist2[h1 & 127u], 1u);
            }
        }
        __syncthreads();
        if (tid < 64) {
            int l = tid;
            unsigned above0 = s_above;
            unsigned c0 = hist2[2 * l], c1 = hist2[2 * l + 1];
            unsigned S = c0 + c1;
#pragma unroll
            for (int o = 1; o < 64; o <<= 1) {
                unsigned t = __shfl_down(S, o);
                if (l + o < 64) S += t;
            }
            unsigned ab2 = __shfl_down(S, 1);
            if (l == 63) ab2 = 0;
            if (above0 + S >= NC && above0 + ab2 < NC) {
                if (above0 + ab2 + c1 >= NC) s_code = (b1 << 7) | (2 * l + 1);
                else                         s_code = (b1 << 7) | (2 * l);
            }
        }
        __syncthreads();
    }
    int code = s_code;

    // compact candidates: all positives with code >= threshold
#pragma unroll
    for (int j = 0; j < 6; ++j) {
#pragma unroll
        for (int p = 0; p < 4; ++p) {
            unsigned int wp = u[j][p];
            unsigned int h0 = wp & 0xffffu, h1 = wp >> 16;
            if (h0 < 0x8000u && (int)h0 >= code) {
                int slot = atomicAdd(&s_cnt, 1);
                if (slot < CMAX) cand[slot] = j * 2048 + tid * 8 + p * 2;
            }
            if (h1 < 0x8000u && (int)h1 >= code) {
                int slot = atomicAdd(&s_cnt, 1);
                if (slot < CMAX) cand[slot] = j * 2048 + tid * 8 + p * 2 + 1;
            }
        }
    }
    __syncthreads();
    int C = s_cnt < CMAX ? s_cnt : CMAX;

    // exact f64 rerank: 4 threads per candidate (wt L3-resident)
    for (int base = 0; base < C; base += 64) {
        int c = base + (tid >> 2), sub = tid & 3;
        if (c < C) {
            const float* wr = wt + (size_t)cand[c] * D_VIT;
            double acc = 0.0;
            for (int k = sub * 4; k < D_VIT; k += 16) {
                float4 wv = *reinterpret_cast<const float4*>(wr + k);
                float4 xv = *reinterpret_cast<const float4*>(xs + k);
                acc += (double)wv.x * xv.x + (double)wv.y * xv.y
                     + (double)wv.z * xv.z + (double)wv.w * xv.w;
            }
            acc += __shfl_xor(acc, 1);
            acc += __shfl_xor(acc, 2);
            if (sub == 0) cval[c] = acc > 0.0 ? acc : 0.0;
        }
    }
    __syncthreads();

    // parallel rank-routing (deterministic regardless of cand order)
    if (tid < C) {
        double mv = cval[tid]; int mi = cand[tid];
        int rank = 0;
        for (int j = 0; j < C; ++j) {
            double vj = cval[j];
            rank += (vj > mv) || (vj == mv && cand[j] < mi);
        }
        if (rank < TOPK) { sval[rank] = (float)mv; sidx[rank] = mi; }
    }
    __syncthreads();

    // sparse decode + b_dec; nt store for out (write-once, full lines)
    for (int d = tid; d < D_VIT; d += 256) {
        float o = bdec[d];
#pragma unroll
        for (int j = 0; j < TOPK; j++)
            o = fmaf(sval[j], wdec[(size_t)sidx[j] * D_VIT + d], o);
        __builtin_nontemporal_store(o, out + (size_t)row * D_VIT + d);
    }
}

extern "C" void kernel_launch(void* const* d_in, const int* in_sizes, int n_in,
                              void* d_out, int out_size, void* d_ws, size_t ws_size,
                              hipStream_t stream) {
    const float* x    = (const float*)d_in[0];
    const float* wenc = (const float*)d_in[1];
    const float* wdec = (const float*)d_in[2];
    const float* bdec = (const float*)d_in[3];
    float* out = (float*)d_out;
    int M = in_sizes[0] / D_VIT;

    size_t wt_b  = (size_t)D_SAE * D_VIT * sizeof(float);
    size_t wtb_b = (size_t)D_SAE * D_VIT * sizeof(__hip_bfloat16);
    size_t xb_b  = (size_t)M * D_VIT * sizeof(__hip_bfloat16);
    size_t fixed = wt_b + wtb_b + xb_b;
    size_t row_b = (size_t)D_SAE * sizeof(__hip_bfloat16);

    float* wt            = (float*)d_ws;
    __hip_bfloat16* wtb  = (__hip_bfloat16*)((char*)d_ws + wt_b);
    __hip_bfloat16* xb   = (__hip_bfloat16*)((char*)d_ws + wt_b + wtb_b);
    __hip_bfloat16* actb = (__hip_bfloat16*)((char*)d_ws + fixed);

    long long chl = (long long)((ws_size > fixed ? ws_size - fixed : row_b) / row_b);
    int CH = (int)(chl < 1 ? 1 : (chl > (long long)M ? M : chl));
    if (CH > CHMAX) CH = CHMAX;           // L3 blocking: acts chunk <= 100MB
    if (CH >= 128 && CH < M) CH &= ~127;

    {
        dim3 g(D_SAE / 32, D_VIT / 32), b(32, 8);
        hipLaunchKernelGGL(k_transpose, g, b, 0, stream, wenc, wt, wtb);
    }
    {
        long long n = (long long)M * D_VIT;
        int blocks = (int)((n / 8 + 255) / 256);
        hipLaunchKernelGGL(k_cvt_x, dim3(blocks), dim3(256), 0, stream, x, bdec, xb, n);
    }
    for (int s = 0; s < M; s += CH) {
        int mr = (M - s) < CH ? (M - s) : CH;
        dim3 ge(D_SAE / EBN, (mr + EBM - 1) / EBM), be(256);
        hipLaunchKernelGGL(k_enc_mfma, ge, be, 0, stream, xb, wtb, actb, s, mr, M);
        hipLaunchKernelGGL(k_select, dim3(mr), dim3(256), 0, stream,
                           actb, x, bdec, wt, wdec, out, s, mr);
    }
}

// Round 8
// 746.861 us; speedup vs baseline: 1.2953x; 1.1845x over previous
//
#include <hip/hip_runtime.h>
#include <hip/hip_bf16.h>
#include <stdint.h>

#define D_VIT 768
#define D_SAE 12288
#define TOPK 32
#define NC 48          // candidate superset target
#define CMAX 128
#define CHMAX 4096     // rows per chunk (L3 blocking)

typedef __attribute__((ext_vector_type(8))) short bf8_t;   // 8 bf16 (4 VGPRs)
typedef __attribute__((ext_vector_type(4))) float f4_t;    // 4 f32 acc
typedef __attribute__((ext_vector_type(4))) unsigned int u32x4;
typedef const __attribute__((address_space(1))) void* gas_t;
typedef __attribute__((address_space(3))) void* las_t;

// ---------------- transpose W_enc (768 x 12288) -> wt f32 + wtb bf16 ---------
__global__ void k_transpose(const float* __restrict__ src, float* __restrict__ dst,
                            __hip_bfloat16* __restrict__ dstb) {
    __shared__ float t[32][33];
    int f0 = blockIdx.x * 32, k0 = blockIdx.y * 32;
    int tx = threadIdx.x, ty = threadIdx.y;
#pragma unroll
    for (int j = 0; j < 32; j += 8)
        t[ty + j][tx] = src[(size_t)(k0 + ty + j) * D_SAE + f0 + tx];
    __syncthreads();
#pragma unroll
    for (int j = 0; j < 32; j += 8) {
        float v = t[tx][ty + j];
        dst[(size_t)(f0 + ty + j) * D_VIT + k0 + tx] = v;
        dstb[(size_t)(f0 + ty + j) * D_VIT + k0 + tx] = __float2bfloat16(v);
    }
}

// ---------------- xb = bf16(x - b_dec) ---------------------------------------
__global__ __launch_bounds__(256) void k_cvt_x(const float* __restrict__ x,
    const float* __restrict__ bdec, __hip_bfloat16* __restrict__ xb, long long n) {
    long long i = ((long long)blockIdx.x * 256 + threadIdx.x) * 8;
    if (i >= n) return;
    float4 a = *reinterpret_cast<const float4*>(x + i);
    float4 b = *reinterpret_cast<const float4*>(x + i + 4);
    int kk = (int)(i % D_VIT);
    float4 c = *reinterpret_cast<const float4*>(bdec + kk);
    float4 d = *reinterpret_cast<const float4*>(bdec + kk + 4);
    union { __hip_bfloat16 h[8]; uint4 v; } o;
    o.h[0] = __float2bfloat16(a.x - c.x); o.h[1] = __float2bfloat16(a.y - c.y);
    o.h[2] = __float2bfloat16(a.z - c.z); o.h[3] = __float2bfloat16(a.w - c.w);
    o.h[4] = __float2bfloat16(b.x - d.x); o.h[5] = __float2bfloat16(b.y - d.y);
    o.h[6] = __float2bfloat16(b.z - d.z); o.h[7] = __float2bfloat16(b.w - d.w);
    *reinterpret_cast<uint4*>(xb + i) = o.v;
}

// ---------------- wdecb = bf16(wdec) -----------------------------------------
__global__ __launch_bounds__(256) void k_cvt_w(const float* __restrict__ wdec,
    __hip_bfloat16* __restrict__ wdecb, long long n) {
    long long i = ((long long)blockIdx.x * 256 + threadIdx.x) * 8;
    if (i >= n) return;
    float4 a = *reinterpret_cast<const float4*>(wdec + i);
    float4 b = *reinterpret_cast<const float4*>(wdec + i + 4);
    union { __hip_bfloat16 h[8]; uint4 v; } o;
    o.h[0] = __float2bfloat16(a.x); o.h[1] = __float2bfloat16(a.y);
    o.h[2] = __float2bfloat16(a.z); o.h[3] = __float2bfloat16(a.w);
    o.h[4] = __float2bfloat16(b.x); o.h[5] = __float2bfloat16(b.y);
    o.h[6] = __float2bfloat16(b.z); o.h[7] = __float2bfloat16(b.w);
    *reinterpret_cast<uint4*>(wdecb + i) = o.v;
}

// ---------------- MFMA encoder: actsb = bf16(relu(xb @ wtb^T)) ---------------
#define EBM 128
#define EBN 128
#define EBK 64

__global__ __launch_bounds__(256) void k_enc_mfma(
    const __hip_bfloat16* __restrict__ xb, const __hip_bfloat16* __restrict__ wtb,
    __hip_bfloat16* __restrict__ actsb, int row0, int mrows, int Mtot) {
    __shared__ __hip_bfloat16 As[EBM * EBK];
    __shared__ __hip_bfloat16 Bs[EBN * EBK];
    int tid = threadIdx.x;
    int lane = tid & 63, w = tid >> 6;
    int wm = w >> 1, wn = w & 1;
    int tile_m = blockIdx.y * EBM, tile_n = blockIdx.x * EBN;

    f4_t acc[4][4] = {};

#pragma unroll 1
    for (int k0 = 0; k0 < D_VIT; k0 += EBK) {
#pragma unroll
        for (int j = 0; j < 4; ++j) {
            int G = w * 64 + j * 256 + lane;
            int rr = G >> 3, g = G & 7;
            int gg = g ^ (rr & 7);
            int ar = row0 + tile_m + rr; if (ar >= Mtot) ar = Mtot - 1;
            const __hip_bfloat16* ga = xb + (size_t)ar * D_VIT + k0 + gg * 8;
            __builtin_amdgcn_global_load_lds((gas_t)ga,
                (las_t)(As + (w * 64 + j * 256) * 8), 16, 0, 0);
            const __hip_bfloat16* gb = wtb + (size_t)(tile_n + rr) * D_VIT + k0 + gg * 8;
            __builtin_amdgcn_global_load_lds((gas_t)gb,
                (las_t)(Bs + (w * 64 + j * 256) * 8), 16, 0, 0);
        }
        __syncthreads();

        int lrow = lane & 15, lk = lane >> 4;
#pragma unroll
        for (int half = 0; half < 2; ++half) {
            int g = lk + half * 4;
            bf8_t af[4], bfr[4];
#pragma unroll
            for (int f = 0; f < 4; ++f) {
                int rr = wm * 64 + f * 16 + lrow;
                af[f] = *reinterpret_cast<const bf8_t*>(As + rr * EBK + ((g ^ (lrow & 7)) << 3));
                int rn = wn * 64 + f * 16 + lrow;
                bfr[f] = *reinterpret_cast<const bf8_t*>(Bs + rn * EBK + ((g ^ (lrow & 7)) << 3));
            }
#pragma unroll
            for (int i = 0; i < 4; ++i)
#pragma unroll
                for (int jn = 0; jn < 4; ++jn)
                    acc[i][jn] = __builtin_amdgcn_mfma_f32_16x16x32_bf16(
                        bfr[jn], af[i], acc[i][jn], 0, 0, 0);
        }
        __syncthreads();
    }

#pragma unroll
    for (int i = 0; i < 4; ++i) {
        int xr = tile_m + wm * 64 + i * 16 + (lane & 15);
        if (xr < mrows) {
            __hip_bfloat16* rowp = actsb + (size_t)xr * D_SAE;
#pragma unroll
            for (int jn = 0; jn < 4; ++jn) {
                int fb = tile_n + wn * 64 + jn * 16 + ((lane >> 4) << 2);
                union { __hip_bfloat16 h[4]; uint2 u; } o;
                o.h[0] = __float2bfloat16(fmaxf(acc[i][jn][0], 0.f));
                o.h[1] = __float2bfloat16(fmaxf(acc[i][jn][1], 0.f));
                o.h[2] = __float2bfloat16(fmaxf(acc[i][jn][2], 0.f));
                o.h[3] = __float2bfloat16(fmaxf(acc[i][jn][3], 0.f));
                *reinterpret_cast<uint2*>(rowp + fb) = o.u;
            }
        }
    }
}

// -------- per-row: threshold -> band-limited f64 rerank -> decode ------------
__global__ __launch_bounds__(256) void k_select(
    const __hip_bfloat16* __restrict__ actsb, const float* __restrict__ x,
    const float* __restrict__ bdec, const float* __restrict__ wt,
    const __hip_bfloat16* __restrict__ wdecb, float* __restrict__ out,
    int row0, int mrows) {
    int lrow = blockIdx.x;
    int row = row0 + lrow;
    int tid = threadIdx.x;

    __shared__ float xs[D_VIT];
    __shared__ unsigned int hist1[256];
    __shared__ unsigned int hist2[128];
    __shared__ int cand[CMAX];
    __shared__ float cvfin[CMAX];
    __shared__ float cexact[CMAX];
    __shared__ unsigned char cflag[CMAX];
    __shared__ int alist[CMAX];
    __shared__ float sval[TOPK];
    __shared__ int sidx[TOPK];
    __shared__ int s_cnt, s_b1, s_code, s_na, s_nd;
    __shared__ unsigned int s_above;
    __shared__ float s_vb;

    hist1[tid] = 0;
    if (tid < 128) { hist2[tid] = 0; cflag[tid] = 0; }
    if (tid < TOPK) { sval[tid] = 0.f; sidx[tid] = 0; }
    if (tid == 0) { s_cnt = 0; s_b1 = -1; s_code = 1; s_above = 0;
                    s_na = 0; s_nd = 0; s_vb = 0.f; }
    for (int i = tid; i < D_VIT; i += 256)
        xs[i] = x[(size_t)row * D_VIT + i] - bdec[i];

    u32x4 u[6];
    const u32x4* arow = reinterpret_cast<const u32x4*>(actsb + (size_t)lrow * D_SAE);
#pragma unroll
    for (int j = 0; j < 6; ++j) u[j] = arow[256 * j + tid];
    __syncthreads();

    // level-1 histogram over exponent byte (positives only)
#pragma unroll
    for (int j = 0; j < 6; ++j) {
#pragma unroll
        for (int p = 0; p < 4; ++p) {
            unsigned int wp = u[j][p];
            unsigned int h0 = wp & 0xffffu, h1 = wp >> 16;
            if (h0 && h0 < 0x8000u) atomicAdd(&hist1[h0 >> 7], 1u);
            if (h1 && h1 < 0x8000u) atomicAdd(&hist1[h1 >> 7], 1u);
        }
    }
    __syncthreads();

    if (tid < 64) {
        int l = tid;
        unsigned c0 = hist1[4 * l], c1 = hist1[4 * l + 1],
                 c2 = hist1[4 * l + 2], c3 = hist1[4 * l + 3];
        unsigned S = c0 + c1 + c2 + c3;
#pragma unroll
        for (int o = 1; o < 64; o <<= 1) {
            unsigned t = __shfl_down(S, o);
            if (l + o < 64) S += t;
        }
        unsigned above = __shfl_down(S, 1);
        if (l == 63) above = 0;
        if (S >= NC && above < NC) {
            int b1; unsigned ab;
            if (above + c3 >= NC)                 { b1 = 4 * l + 3; ab = above; }
            else if (above + c3 + c2 >= NC)       { b1 = 4 * l + 2; ab = above + c3; }
            else if (above + c3 + c2 + c1 >= NC)  { b1 = 4 * l + 1; ab = above + c3 + c2; }
            else                                  { b1 = 4 * l;     ab = above + c3 + c2 + c1; }
            s_b1 = b1; s_above = ab;
        }
    }
    __syncthreads();
    int b1 = s_b1;

    if (b1 >= 0) {
#pragma unroll
        for (int j = 0; j < 6; ++j) {
#pragma unroll
            for (int p = 0; p < 4; ++p) {
                unsigned int wp = u[j][p];
                unsigned int h0 = wp & 0xffffu, h1 = wp >> 16;
                if (h0 && h0 < 0x8000u && (int)(h0 >> 7) == b1) atomicAdd(&hist2[h0 & 127u], 1u);
                if (h1 && h1 < 0x8000u && (int)(h1 >> 7) == b1) atomicAdd(&hist2[h1 & 127u], 1u);
            }
        }
        __syncthreads();
        if (tid < 64) {
            int l = tid;
            unsigned above0 = s_above;
            unsigned c0 = hist2[2 * l], c1 = hist2[2 * l + 1];
            unsigned S = c0 + c1;
#pragma unroll
            for (int o = 1; o < 64; o <<= 1) {
                unsigned t = __shfl_down(S, o);
                if (l + o < 64) S += t;
            }
            unsigned ab2 = __shfl_down(S, 1);
            if (l == 63) ab2 = 0;
            if (above0 + S >= NC && above0 + ab2 < NC) {
                if (above0 + ab2 + c1 >= NC) s_code = (b1 << 7) | (2 * l + 1);
                else                         s_code = (b1 << 7) | (2 * l);
            }
        }
        __syncthreads();
    }
    int code = s_code;

    // compact candidates, packed (code<<16)|idx
#pragma unroll
    for (int j = 0; j < 6; ++j) {
#pragma unroll
        for (int p = 0; p < 4; ++p) {
            unsigned int wp = u[j][p];
            unsigned int h0 = wp & 0xffffu, h1 = wp >> 16;
            if (h0 < 0x8000u && (int)h0 >= code) {
                int slot = atomicAdd(&s_cnt, 1);
                if (slot < CMAX) cand[slot] = (int)((h0 << 16) | (unsigned)(j * 2048 + tid * 8 + p * 2));
            }
            if (h1 < 0x8000u && (int)h1 >= code) {
                int slot = atomicAdd(&s_cnt, 1);
                if (slot < CMAX) cand[slot] = (int)((h1 << 16) | (unsigned)(j * 2048 + tid * 8 + p * 2 + 1));
            }
        }
    }
    __syncthreads();
    int C = s_cnt < CMAX ? s_cnt : CMAX;

    // code-rank; vb = 32nd largest bf16 value
    int myidx = 0; float myval = 0.f;
    if (tid < C) {
        unsigned mypack = (unsigned)cand[tid];
        unsigned mycode = mypack >> 16; myidx = (int)(mypack & 0xffffu);
        myval = __uint_as_float(mycode << 16);
        int myrank = 0;
        for (int j = 0; j < C; ++j) {
            unsigned pj = (unsigned)cand[j];
            unsigned cj = pj >> 16; int ij = (int)(pj & 0xffffu);
            myrank += (cj > mycode) || (cj == mycode && ij < myidx);
        }
        if (C > 32 && myrank == 31) s_vb = myval;
    }
    __syncthreads();

    // partition: definite-in (D) / ambiguous band (A) / excluded
    if (tid < C) {
        if (C <= 32) { cflag[tid] = 2; cvfin[tid] = myval; }
        else {
            float vb = s_vb;
            float band = 0.025f + 0.018f * vb;
            if (myval > vb + band) { cflag[tid] = 2; cvfin[tid] = myval; atomicAdd(&s_nd, 1); }
            else if (myval >= vb - band) { int a = atomicAdd(&s_na, 1); alist[a] = tid; cflag[tid] = 1; }
        }
    }
    __syncthreads();
    int na = s_na, nd = s_nd;

    // f64 rerank of band only: 8 cands x 32 threads
    for (int base = 0; base < na; base += 8) {
        int ai = base + (tid >> 5), sub = tid & 31;
        if (ai < na) {
            int c = alist[ai];
            int f = (int)(((unsigned)cand[c]) & 0xffffu);
            const float* wr = wt + (size_t)f * D_VIT;
            double acc = 0.0;
            for (int k = sub * 4; k < D_VIT; k += 128) {
                float4 wv = *reinterpret_cast<const float4*>(wr + k);
                float4 xv = *reinterpret_cast<const float4*>(xs + k);
                acc += (double)wv.x * xv.x + (double)wv.y * xv.y
                     + (double)wv.z * xv.z + (double)wv.w * xv.w;
            }
            acc += __shfl_xor(acc, 1);  acc += __shfl_xor(acc, 2);
            acc += __shfl_xor(acc, 4);  acc += __shfl_xor(acc, 8);
            acc += __shfl_xor(acc, 16);
            if (sub == 0) cexact[c] = (float)(acc > 0.0 ? acc : 0.0);
        }
    }
    __syncthreads();

    // choose top (32-nd) of the band by exact value
    if (C > 32 && tid < C && cflag[tid] == 1) {
        int kq = TOPK - nd;
        float ex = cexact[tid]; int rankA = 0;
        for (int j = 0; j < na; ++j) {
            int cj = alist[j];
            float ej = cexact[cj]; int ij = (int)(((unsigned)cand[cj]) & 0xffffu);
            rankA += (ej > ex) || (ej == ex && ij < myidx);
        }
        if (rankA < kq) { cflag[tid] = 3; cvfin[tid] = ex; }
    }
    __syncthreads();

    // deterministic slot routing among the chosen (content-based comparator)
    if (tid < C && cflag[tid] >= 2) {
        float mv = cvfin[tid]; int rank = 0;
        for (int j = 0; j < C; ++j) {
            if (cflag[j] >= 2) {
                float vj = cvfin[j]; int ij = (int)(((unsigned)cand[j]) & 0xffffu);
                rank += (vj > mv) || (vj == mv && ij < myidx);
            }
        }
        if (rank < TOPK) { sval[rank] = mv; sidx[rank] = myidx; }
    }
    __syncthreads();

    // sparse decode from bf16 wdec + b_dec; nt store (write-once full lines)
    for (int d = tid; d < D_VIT; d += 256) {
        float o = bdec[d];
#pragma unroll
        for (int j = 0; j < TOPK; j++)
            o = fmaf(sval[j], __bfloat162float(wdecb[(size_t)sidx[j] * D_VIT + d]), o);
        __builtin_nontemporal_store(o, out + (size_t)row * D_VIT + d);
    }
}

extern "C" void kernel_launch(void* const* d_in, const int* in_sizes, int n_in,
                              void* d_out, int out_size, void* d_ws, size_t ws_size,
                              hipStream_t stream) {
    const float* x    = (const float*)d_in[0];
    const float* wenc = (const float*)d_in[1];
    const float* wdec = (const float*)d_in[2];
    const float* bdec = (const float*)d_in[3];
    float* out = (float*)d_out;
    int M = in_sizes[0] / D_VIT;

    size_t wt_b    = (size_t)D_SAE * D_VIT * sizeof(float);
    size_t wtb_b   = (size_t)D_SAE * D_VIT * sizeof(__hip_bfloat16);
    size_t xb_b    = (size_t)M * D_VIT * sizeof(__hip_bfloat16);
    size_t wdecb_b = (size_t)D_SAE * D_VIT * sizeof(__hip_bfloat16);
    size_t fixed   = wt_b + wtb_b + xb_b + wdecb_b;
    size_t row_b   = (size_t)D_SAE * sizeof(__hip_bfloat16);

    float* wt             = (float*)d_ws;
    __hip_bfloat16* wtb   = (__hip_bfloat16*)((char*)d_ws + wt_b);
    __hip_bfloat16* xb    = (__hip_bfloat16*)((char*)d_ws + wt_b + wtb_b);
    __hip_bfloat16* wdecb = (__hip_bfloat16*)((char*)d_ws + wt_b + wtb_b + xb_b);
    __hip_bfloat16* actb  = (__hip_bfloat16*)((char*)d_ws + fixed);

    long long chl = (long long)((ws_size > fixed ? ws_size - fixed : row_b) / row_b);
    int CH = (int)(chl < 1 ? 1 : (chl > (long long)M ? M : chl));
    if (CH > CHMAX) CH = CHMAX;
    if (CH >= 128 && CH < M) CH &= ~127;

    {
        dim3 g(D_SAE / 32, D_VIT / 32), b(32, 8);
        hipLaunchKernelGGL(k_transpose, g, b, 0, stream, wenc, wt, wtb);
    }
    {
        long long n = (long long)M * D_VIT;
        int blocks = (int)((n / 8 + 255) / 256);
        hipLaunchKernelGGL(k_cvt_x, dim3(blocks), dim3(256), 0, stream, x, bdec, xb, n);
    }
    {
        long long n = (long long)D_SAE * D_VIT;
        int blocks = (int)((n / 8 + 255) / 256);
        hipLaunchKernelGGL(k_cvt_w, dim3(blocks), dim3(256), 0, stream, wdec, wdecb, n);
    }
    for (int s = 0; s < M; s += CH) {
        int mr = (M - s) < CH ? (M - s) : CH;
        dim3 ge(D_SAE / EBN, (mr + EBM - 1) / EBM), be(256);
        hipLaunchKernelGGL(k_enc_mfma, ge, be, 0, stream, xb, wtb, actb, s, mr, M);
        hipLaunchKernelGGL(k_select, dim3(mr), dim3(256), 0, stream,
                           actb, x, bdec, wt, wdecb, out, s, mr);
    }
}

// Round 9
// 710.662 us; speedup vs baseline: 1.3613x; 1.0509x over previous
//
#include <hip/hip_runtime.h>
#include <hip/hip_bf16.h>
#include <stdint.h>

#define D_VIT 768
#define D_SAE 12288
#define TOPK 32
#define NC 48          // candidate superset target
#define CMAX 128
#define CHMAX 4096     // rows per chunk (L3 blocking)

typedef __attribute__((ext_vector_type(8))) short bf8_t;   // 8 bf16 (4 VGPRs)
typedef __attribute__((ext_vector_type(4))) float f4_t;    // 4 f32 acc
typedef __attribute__((ext_vector_type(4))) unsigned int u32x4;
typedef const __attribute__((address_space(1))) void* gas_t;
typedef __attribute__((address_space(3))) void* las_t;

// ---------------- transpose W_enc (768 x 12288) -> wt f32 + wtb bf16 ---------
__global__ void k_transpose(const float* __restrict__ src, float* __restrict__ dst,
                            __hip_bfloat16* __restrict__ dstb) {
    __shared__ float t[32][33];
    int f0 = blockIdx.x * 32, k0 = blockIdx.y * 32;
    int tx = threadIdx.x, ty = threadIdx.y;
#pragma unroll
    for (int j = 0; j < 32; j += 8)
        t[ty + j][tx] = src[(size_t)(k0 + ty + j) * D_SAE + f0 + tx];
    __syncthreads();
#pragma unroll
    for (int j = 0; j < 32; j += 8) {
        float v = t[tx][ty + j];
        dst[(size_t)(f0 + ty + j) * D_VIT + k0 + tx] = v;
        dstb[(size_t)(f0 + ty + j) * D_VIT + k0 + tx] = __float2bfloat16(v);
    }
}

// ---------------- xb = bf16(x - b_dec) ---------------------------------------
__global__ __launch_bounds__(256) void k_cvt_x(const float* __restrict__ x,
    const float* __restrict__ bdec, __hip_bfloat16* __restrict__ xb, long long n) {
    long long i = ((long long)blockIdx.x * 256 + threadIdx.x) * 8;
    if (i >= n) return;
    float4 a = *reinterpret_cast<const float4*>(x + i);
    float4 b = *reinterpret_cast<const float4*>(x + i + 4);
    int kk = (int)(i % D_VIT);
    float4 c = *reinterpret_cast<const float4*>(bdec + kk);
    float4 d = *reinterpret_cast<const float4*>(bdec + kk + 4);
    union { __hip_bfloat16 h[8]; uint4 v; } o;
    o.h[0] = __float2bfloat16(a.x - c.x); o.h[1] = __float2bfloat16(a.y - c.y);
    o.h[2] = __float2bfloat16(a.z - c.z); o.h[3] = __float2bfloat16(a.w - c.w);
    o.h[4] = __float2bfloat16(b.x - d.x); o.h[5] = __float2bfloat16(b.y - d.y);
    o.h[6] = __float2bfloat16(b.z - d.z); o.h[7] = __float2bfloat16(b.w - d.w);
    *reinterpret_cast<uint4*>(xb + i) = o.v;
}

// ---------------- wdecb = bf16(wdec) -----------------------------------------
__global__ __launch_bounds__(256) void k_cvt_w(const float* __restrict__ wdec,
    __hip_bfloat16* __restrict__ wdecb, long long n) {
    long long i = ((long long)blockIdx.x * 256 + threadIdx.x) * 8;
    if (i >= n) return;
    float4 a = *reinterpret_cast<const float4*>(wdec + i);
    float4 b = *reinterpret_cast<const float4*>(wdec + i + 4);
    union { __hip_bfloat16 h[8]; uint4 v; } o;
    o.h[0] = __float2bfloat16(a.x); o.h[1] = __float2bfloat16(a.y);
    o.h[2] = __float2bfloat16(a.z); o.h[3] = __float2bfloat16(a.w);
    o.h[4] = __float2bfloat16(b.x); o.h[5] = __float2bfloat16(b.y);
    o.h[6] = __float2bfloat16(b.z); o.h[7] = __float2bfloat16(b.w);
    *reinterpret_cast<uint4*>(wdecb + i) = o.v;
}

// ------- 256x256x64 8-wave double-buffered MFMA encoder (T2+T3+T4+T5) --------
#define GBM 256
#define GBN 256
#define GBK 64
#define NKT (D_VIT / GBK)   // 12

__global__ __launch_bounds__(512, 2) void k_enc8(
    const __hip_bfloat16* __restrict__ xb, const __hip_bfloat16* __restrict__ wtb,
    __hip_bfloat16* __restrict__ actsb, int row0, int mrows, int Mtot) {
    __shared__ __hip_bfloat16 lds[2][2][GBM * GBK];   // 128 KiB: [buf][A/B][256][64]
    int tid = threadIdx.x;
    int lane = tid & 63, w = tid >> 6;
    int wm = w >> 2, wn = w & 3;                      // 2 x 4 waves
    int tile_m = blockIdx.y * GBM, tile_n = blockIdx.x * GBN;
    int lrow = lane & 15, lk = lane >> 4;
    int G0 = w * 64 + lane;                           // staging granule, j=0

    f4_t acc[2][4][2][2] = {};                        // [mq][f][nq][g]

    // stage half-tile h of K-tile kt into buffer b.
    // h: 0=A rows0-127, 1=B rows0-127, 2=A rows128-255, 3=B rows128-255
    // LDS linear dest + inverse-swizzled global source (rule #21; same
    // (row&7) XOR as the read side).
    auto STAGE = [&](int kt, int h, int b) {
#pragma unroll
        for (int j = 0; j < 2; ++j) {
            int G = G0 + j * 512;
            int r = G >> 3, s = G & 7;
            int gg = s ^ (r & 7);
            int half = h >> 1;
            if ((h & 1) == 0) {
                int ar = row0 + tile_m + half * 128 + r;
                if (ar >= Mtot) ar = Mtot - 1;
                const __hip_bfloat16* src = xb + (size_t)ar * D_VIT + kt * GBK + gg * 8;
                __builtin_amdgcn_global_load_lds((gas_t)src,
                    (las_t)(&lds[b][0][half * 8192 + (w * 64 + j * 512) * 8]), 16, 0, 0);
            } else {
                int br = tile_n + half * 128 + r;
                const __hip_bfloat16* src = wtb + (size_t)br * D_VIT + kt * GBK + gg * 8;
                __builtin_amdgcn_global_load_lds((gas_t)src,
                    (las_t)(&lds[b][1][half * 8192 + (w * 64 + j * 512) * 8]), 16, 0, 0);
            }
        }
    };

    // one quadrant phase: 12 ds_read_b128 + 16 MFMA (setprio-wrapped).
    // MQ/NQ must be compile-time (rule #20: static acc indexing).
#define PHASE(MQ, NQ, BUF) do {                                                \
        const __hip_bfloat16* Ab = &lds[BUF][0][0];                            \
        const __hip_bfloat16* Bb = &lds[BUF][1][0];                            \
        bf8_t af[4][2], bv[2][2];                                              \
        _Pragma("unroll")                                                      \
        for (int f = 0; f < 4; ++f) {                                          \
            int ra = wm * 128 + (MQ) * 64 + f * 16 + lrow;                     \
            _Pragma("unroll")                                                  \
            for (int h = 0; h < 2; ++h) {                                      \
                int sl = (lk + 4 * h) ^ (ra & 7);                              \
                af[f][h] = *reinterpret_cast<const bf8_t*>(Ab + ra * GBK + sl * 8); \
            }                                                                  \
        }                                                                      \
        _Pragma("unroll")                                                      \
        for (int g = 0; g < 2; ++g) {                                          \
            int rb = wn * 64 + (NQ) * 32 + g * 16 + lrow;                      \
            _Pragma("unroll")                                                  \
            for (int h = 0; h < 2; ++h) {                                      \
                int sl = (lk + 4 * h) ^ (rb & 7);                              \
                bv[g][h] = *reinterpret_cast<const bf8_t*>(Bb + rb * GBK + sl * 8); \
            }                                                                  \
        }                                                                      \
        __builtin_amdgcn_s_setprio(1);                                         \
        _Pragma("unroll")                                                      \
        for (int h = 0; h < 2; ++h)                                            \
            _Pragma("unroll")                                                  \
            for (int f = 0; f < 4; ++f)                                        \
                _Pragma("unroll")                                              \
                for (int g = 0; g < 2; ++g)                                    \
                    acc[MQ][f][NQ][g] = __builtin_amdgcn_mfma_f32_16x16x32_bf16( \
                        bv[g][h], af[f][h], acc[MQ][f][NQ][g], 0, 0, 0);       \
        __builtin_amdgcn_s_setprio(0);                                         \
    } while (0)

    // prologue: stage all of K-tile 0 into buf0 (8 loads in flight)
#pragma unroll
    for (int h = 0; h < 4; ++h) STAGE(0, h, 0);

    int cur = 0;
#pragma unroll 1
    for (int t = 0; t < NKT; ++t) {
        int nb = cur ^ 1;
        bool pf = (t + 1 < NKT);
        if (pf) STAGE(t + 1, 0, nb);
        // counted wait: retire tile t's 8 loads, keep the 2 just issued in flight
        if (pf) asm volatile("s_waitcnt vmcnt(2)" ::: "memory");
        else    asm volatile("s_waitcnt vmcnt(0)" ::: "memory");
        __builtin_amdgcn_s_barrier();            // all waves' tile-t data visible
        asm volatile("" ::: "memory");
        __builtin_amdgcn_sched_barrier(0);
        PHASE(0, 0, cur);
        if (pf) STAGE(t + 1, 1, nb);
        PHASE(1, 0, cur);
        if (pf) STAGE(t + 1, 2, nb);
        PHASE(0, 1, cur);
        if (pf) STAGE(t + 1, 3, nb);
        PHASE(1, 1, cur);
        asm volatile("" ::: "memory");
        __builtin_amdgcn_s_barrier();            // all reads of buf[cur] done
        asm volatile("" ::: "memory");
        cur = nb;
    }
#undef PHASE

    // C-write: D[feature][xrow] -> 4 consecutive features per lane, uint2 stores
#pragma unroll
    for (int mq = 0; mq < 2; ++mq)
#pragma unroll
        for (int f = 0; f < 4; ++f) {
            int xr = tile_m + wm * 128 + mq * 64 + f * 16 + lrow;
            if (xr < mrows) {
                __hip_bfloat16* rowp = actsb + (size_t)xr * D_SAE;
#pragma unroll
                for (int nq = 0; nq < 2; ++nq)
#pragma unroll
                    for (int g = 0; g < 2; ++g) {
                        int fb = tile_n + wn * 64 + nq * 32 + g * 16 + lk * 4;
                        union { __hip_bfloat16 h4[4]; uint2 u; } o;
                        o.h4[0] = __float2bfloat16(fmaxf(acc[mq][f][nq][g][0], 0.f));
                        o.h4[1] = __float2bfloat16(fmaxf(acc[mq][f][nq][g][1], 0.f));
                        o.h4[2] = __float2bfloat16(fmaxf(acc[mq][f][nq][g][2], 0.f));
                        o.h4[3] = __float2bfloat16(fmaxf(acc[mq][f][nq][g][3], 0.f));
                        *reinterpret_cast<uint2*>(rowp + fb) = o.u;
                    }
            }
        }
}

// -------- per-row: threshold -> band-limited f64 rerank -> decode ------------
__global__ __launch_bounds__(256) void k_select(
    const __hip_bfloat16* __restrict__ actsb, const float* __restrict__ x,
    const float* __restrict__ bdec, const float* __restrict__ wt,
    const __hip_bfloat16* __restrict__ wdecb, float* __restrict__ out,
    int row0, int mrows) {
    int lrow = blockIdx.x;
    int row = row0 + lrow;
    int tid = threadIdx.x;

    __shared__ float xs[D_VIT];
    __shared__ unsigned int hist1[256];
    __shared__ unsigned int hist2[128];
    __shared__ int cand[CMAX];
    __shared__ float cvfin[CMAX];
    __shared__ float cexact[CMAX];
    __shared__ unsigned char cflag[CMAX];
    __shared__ int alist[CMAX];
    __shared__ float sval[TOPK];
    __shared__ int sidx[TOPK];
    __shared__ int s_cnt, s_b1, s_code, s_na, s_nd;
    __shared__ unsigned int s_above;
    __shared__ float s_vb;

    hist1[tid] = 0;
    if (tid < 128) { hist2[tid] = 0; cflag[tid] = 0; }
    if (tid < TOPK) { sval[tid] = 0.f; sidx[tid] = 0; }
    if (tid == 0) { s_cnt = 0; s_b1 = -1; s_code = 1; s_above = 0;
                    s_na = 0; s_nd = 0; s_vb = 0.f; }
    for (int i = tid; i < D_VIT; i += 256)
        xs[i] = x[(size_t)row * D_VIT + i] - bdec[i];

    u32x4 u[6];
    const u32x4* arow = reinterpret_cast<const u32x4*>(actsb + (size_t)lrow * D_SAE);
#pragma unroll
    for (int j = 0; j < 6; ++j) u[j] = arow[256 * j + tid];
    __syncthreads();

    // level-1 histogram over exponent byte (positives only)
#pragma unroll
    for (int j = 0; j < 6; ++j) {
#pragma unroll
        for (int p = 0; p < 4; ++p) {
            unsigned int wp = u[j][p];
            unsigned int h0 = wp & 0xffffu, h1 = wp >> 16;
            if (h0 && h0 < 0x8000u) atomicAdd(&hist1[h0 >> 7], 1u);
            if (h1 && h1 < 0x8000u) atomicAdd(&hist1[h1 >> 7], 1u);
        }
    }
    __syncthreads();

    if (tid < 64) {
        int l = tid;
        unsigned c0 = hist1[4 * l], c1 = hist1[4 * l + 1],
                 c2 = hist1[4 * l + 2], c3 = hist1[4 * l + 3];
        unsigned S = c0 + c1 + c2 + c3;
#pragma unroll
        for (int o = 1; o < 64; o <<= 1) {
            unsigned t = __shfl_down(S, o);
            if (l + o < 64) S += t;
        }
        unsigned above = __shfl_down(S, 1);
        if (l == 63) above = 0;
        if (S >= NC && above < NC) {
            int b1; unsigned ab;
            if (above + c3 >= NC)                 { b1 = 4 * l + 3; ab = above; }
            else if (above + c3 + c2 >= NC)       { b1 = 4 * l + 2; ab = above + c3; }
            else if (above + c3 + c2 + c1 >= NC)  { b1 = 4 * l + 1; ab = above + c3 + c2; }
            else                                  { b1 = 4 * l;     ab = above + c3 + c2 + c1; }
            s_b1 = b1; s_above = ab;
        }
    }
    __syncthreads();
    int b1 = s_b1;

    if (b1 >= 0) {
#pragma unroll
        for (int j = 0; j < 6; ++j) {
#pragma unroll
            for (int p = 0; p < 4; ++p) {
                unsigned int wp = u[j][p];
                unsigned int h0 = wp & 0xffffu, h1 = wp >> 16;
                if (h0 && h0 < 0x8000u && (int)(h0 >> 7) == b1) atomicAdd(&hist2[h0 & 127u], 1u);
                if (h1 && h1 < 0x8000u && (int)(h1 >> 7) == b1) atomicAdd(&hist2[h1 & 127u], 1u);
            }
        }
        __syncthreads();
        if (tid < 64) {
            int l = tid;
            unsigned above0 = s_above;
            unsigned c0 = hist2[2 * l], c1 = hist2[2 * l + 1];
            unsigned S = c0 + c1;
#pragma unroll
            for (int o = 1; o < 64; o <<= 1) {
                unsigned t = __shfl_down(S, o);
                if (l + o < 64) S += t;
            }
            unsigned ab2 = __shfl_down(S, 1);
            if (l == 63) ab2 = 0;
            if (above0 + S >= NC && above0 + ab2 < NC) {
                if (above0 + ab2 + c1 >= NC) s_code = (b1 << 7) | (2 * l + 1);
                else                         s_code = (b1 << 7) | (2 * l);
            }
        }
        __syncthreads();
    }
    int code = s_code;

    // compact candidates, packed (code<<16)|idx
#pragma unroll
    for (int j = 0; j < 6; ++j) {
#pragma unroll
        for (int p = 0; p < 4; ++p) {
            unsigned int wp = u[j][p];
            unsigned int h0 = wp & 0xffffu, h1 = wp >> 16;
            if (h0 < 0x8000u && (int)h0 >= code) {
                int slot = atomicAdd(&s_cnt, 1);
                if (slot < CMAX) cand[slot] = (int)((h0 << 16) | (unsigned)(j * 2048 + tid * 8 + p * 2));
            }
            if (h1 < 0x8000u && (int)h1 >= code) {
                int slot = atomicAdd(&s_cnt, 1);
                if (slot < CMAX) cand[slot] = (int)((h1 << 16) | (unsigned)(j * 2048 + tid * 8 + p * 2 + 1));
            }
        }
    }
    __syncthreads();
    int C = s_cnt < CMAX ? s_cnt : CMAX;

    // code-rank; vb = 32nd largest bf16 value
    int myidx = 0; float myval = 0.f;
    if (tid < C) {
        unsigned mypack = (unsigned)cand[tid];
        unsigned mycode = mypack >> 16; myidx = (int)(mypack & 0xffffu);
        myval = __uint_as_float(mycode << 16);
        int myrank = 0;
        for (int j = 0; j < C; ++j) {
            unsigned pj = (unsigned)cand[j];
            unsigned cj = pj >> 16; int ij = (int)(pj & 0xffffu);
            myrank += (cj > mycode) || (cj == mycode && ij < myidx);
        }
        if (C > 32 && myrank == 31) s_vb = myval;
    }
    __syncthreads();

    // partition: definite-in / ambiguous band / excluded
    if (tid < C) {
        if (C <= 32) { cflag[tid] = 2; cvfin[tid] = myval; }
        else {
            float vb = s_vb;
            float band = 0.025f + 0.018f * vb;
            if (myval > vb + band) { cflag[tid] = 2; cvfin[tid] = myval; atomicAdd(&s_nd, 1); }
            else if (myval >= vb - band) { int a = atomicAdd(&s_na, 1); alist[a] = tid; cflag[tid] = 1; }
        }
    }
    __syncthreads();
    int na = s_na, nd = s_nd;

    // f64 rerank of band only: 8 cands x 32 threads
    for (int base = 0; base < na; base += 8) {
        int ai = base + (tid >> 5), sub = tid & 31;
        if (ai < na) {
            int c = alist[ai];
            int f = (int)(((unsigned)cand[c]) & 0xffffu);
            const float* wr = wt + (size_t)f * D_VIT;
            double acc = 0.0;
            for (int k = sub * 4; k < D_VIT; k += 128) {
                float4 wv = *reinterpret_cast<const float4*>(wr + k);
                float4 xv = *reinterpret_cast<const float4*>(xs + k);
                acc += (double)wv.x * xv.x + (double)wv.y * xv.y
                     + (double)wv.z * xv.z + (double)wv.w * xv.w;
            }
            acc += __shfl_xor(acc, 1);  acc += __shfl_xor(acc, 2);
            acc += __shfl_xor(acc, 4);  acc += __shfl_xor(acc, 8);
            acc += __shfl_xor(acc, 16);
            if (sub == 0) cexact[c] = (float)(acc > 0.0 ? acc : 0.0);
        }
    }
    __syncthreads();

    // choose top (32-nd) of the band by exact value
    if (C > 32 && tid < C && cflag[tid] == 1) {
        int kq = TOPK - nd;
        float ex = cexact[tid]; int rankA = 0;
        for (int j = 0; j < na; ++j) {
            int cj = alist[j];
            float ej = cexact[cj]; int ij = (int)(((unsigned)cand[cj]) & 0xffffu);
            rankA += (ej > ex) || (ej == ex && ij < myidx);
        }
        if (rankA < kq) { cflag[tid] = 3; cvfin[tid] = ex; }
    }
    __syncthreads();

    // deterministic slot routing among the chosen
    if (tid < C && cflag[tid] >= 2) {
        float mv = cvfin[tid]; int rank = 0;
        for (int j = 0; j < C; ++j) {
            if (cflag[j] >= 2) {
                float vj = cvfin[j]; int ij = (int)(((unsigned)cand[j]) & 0xffffu);
                rank += (vj > mv) || (vj == mv && ij < myidx);
            }
        }
        if (rank < TOPK) { sval[rank] = mv; sidx[rank] = myidx; }
    }
    __syncthreads();

    // sparse decode from bf16 wdec + b_dec; nt store (write-once full lines)
    for (int d = tid; d < D_VIT; d += 256) {
        float o = bdec[d];
#pragma unroll
        for (int j = 0; j < TOPK; j++)
            o = fmaf(sval[j], __bfloat162float(wdecb[(size_t)sidx[j] * D_VIT + d]), o);
        __builtin_nontemporal_store(o, out + (size_t)row * D_VIT + d);
    }
}

extern "C" void kernel_launch(void* const* d_in, const int* in_sizes, int n_in,
                              void* d_out, int out_size, void* d_ws, size_t ws_size,
                              hipStream_t stream) {
    const float* x    = (const float*)d_in[0];
    const float* wenc = (const float*)d_in[1];
    const float* wdec = (const float*)d_in[2];
    const float* bdec = (const float*)d_in[3];
    float* out = (float*)d_out;
    int M = in_sizes[0] / D_VIT;

    size_t wt_b    = (size_t)D_SAE * D_VIT * sizeof(float);
    size_t wtb_b   = (size_t)D_SAE * D_VIT * sizeof(__hip_bfloat16);
    size_t xb_b    = (size_t)M * D_VIT * sizeof(__hip_bfloat16);
    size_t wdecb_b = (size_t)D_SAE * D_VIT * sizeof(__hip_bfloat16);
    size_t fixed   = wt_b + wtb_b + xb_b + wdecb_b;
    size_t row_b   = (size_t)D_SAE * sizeof(__hip_bfloat16);

    float* wt             = (float*)d_ws;
    __hip_bfloat16* wtb   = (__hip_bfloat16*)((char*)d_ws + wt_b);
    __hip_bfloat16* xb    = (__hip_bfloat16*)((char*)d_ws + wt_b + wtb_b);
    __hip_bfloat16* wdecb = (__hip_bfloat16*)((char*)d_ws + wt_b + wtb_b + xb_b);
    __hip_bfloat16* actb  = (__hip_bfloat16*)((char*)d_ws + fixed);

    long long chl = (long long)((ws_size > fixed ? ws_size - fixed : row_b) / row_b);
    int CH = (int)(chl < 1 ? 1 : (chl > (long long)M ? M : chl));
    if (CH > CHMAX) CH = CHMAX;
    if (CH >= 256 && CH < M) CH &= ~255;

    {
        dim3 g(D_SAE / 32, D_VIT / 32), b(32, 8);
        hipLaunchKernelGGL(k_transpose, g, b, 0, stream, wenc, wt, wtb);
    }
    {
        long long n = (long long)M * D_VIT;
        int blocks = (int)((n / 8 + 255) / 256);
        hipLaunchKernelGGL(k_cvt_x, dim3(blocks), dim3(256), 0, stream, x, bdec, xb, n);
    }
    {
        long long n = (long long)D_SAE * D_VIT;
        int blocks = (int)((n / 8 + 255) / 256);
        hipLaunchKernelGGL(k_cvt_w, dim3(blocks), dim3(256), 0, stream, wdec, wdecb, n);
    }
    for (int s = 0; s < M; s += CH) {
        int mr = (M - s) < CH ? (M - s) : CH;
        dim3 ge(D_SAE / GBN, (mr + GBM - 1) / GBM), be(512);
        hipLaunchKernelGGL(k_enc8, ge, be, 0, stream, xb, wtb, actb, s, mr, M);
        hipLaunchKernelGGL(k_select, dim3(mr), dim3(256), 0, stream,
                           actb, x, bdec, wt, wdecb, out, s, mr);
    }
}